// Round 7
// baseline (997.767 us; speedup 1.0000x reference)
//
#include <hip/hip_runtime.h>
#include <hip/hip_bf16.h>
#include <math.h>

#define IN_F 128
#define HID 512
#define NH 8

// ---------------------------------------------------------------- utilities

__device__ __forceinline__ float wave_reduce(float v) {
#pragma unroll
  for (int s = 32; s > 0; s >>= 1) v += __shfl_down(v, s, 64);
  return v;
}

// ---------------------------------------------------------------- wa1 = per-head W1 @ a1  (folds attention vectors through W1)
// wa1s[h][k] = sum_c W1[k, h*512+c] * a1_src[h, c]   (shape [8][128])
__global__ __launch_bounds__(256) void k_wa1(const float* __restrict__ W1,
                                             const float* __restrict__ a1s,
                                             const float* __restrict__ a1d,
                                             float* __restrict__ wa1s,
                                             float* __restrict__ wa1d) {
  int w = (blockIdx.x * blockDim.x + threadIdx.x) >> 6;  // wave id: (h,k)
  int lane = threadIdx.x & 63;
  if (w >= NH * IN_F) return;
  int h = w >> 7;
  int k = w & 127;
  const float* wrow = W1 + (size_t)k * (NH * HID) + h * HID;
  const float* as = a1s + h * HID;
  const float* ad = a1d + h * HID;
  int c = lane * 8;
  float4 w0 = *(const float4*)(wrow + c);
  float4 w1 = *(const float4*)(wrow + c + 4);
  float4 s0 = *(const float4*)(as + c);
  float4 s1 = *(const float4*)(as + c + 4);
  float4 d0 = *(const float4*)(ad + c);
  float4 d1 = *(const float4*)(ad + c + 4);
  float ss = w0.x * s0.x + w0.y * s0.y + w0.z * s0.z + w0.w * s0.w +
             w1.x * s1.x + w1.y * s1.y + w1.z * s1.z + w1.w * s1.w;
  float sd = w0.x * d0.x + w0.y * d0.y + w0.z * d0.z + w0.w * d0.w +
             w1.x * d1.x + w1.y * d1.y + w1.z * d1.z + w1.w * d1.w;
  ss = wave_reduce(ss);
  sd = wave_reduce(sd);
  if (lane == 0) { wa1s[h * IN_F + k] = ss; wa1d[h * IN_F + k] = sd; }
}

// ---------------------------------------------------------------- al1 = x @ wa1^T  -> [N,8] each
__global__ __launch_bounds__(256) void k_al1(const float* __restrict__ x,
                                             const float* __restrict__ wa1s,
                                             const float* __restrict__ wa1d,
                                             float* __restrict__ al1s,
                                             float* __restrict__ al1d, int nN) {
  __shared__ float ls[NH * 132];   // padded stride 132 to kill 8-way bank conflict
  __shared__ float ldd[NH * 132];
  for (int i = threadIdx.x; i < NH * IN_F; i += 256) {
    int h = i >> 7, k = i & 127;
    ls[h * 132 + k] = wa1s[i];
    ldd[h * 132 + k] = wa1d[i];
  }
  __syncthreads();
  int gid = blockIdx.x * 256 + threadIdx.x;
  if (gid >= nN * NH) return;
  int n = gid >> 3, h = gid & 7;
  const float* xr = x + (size_t)n * IN_F;
  const float* ws = ls + h * 132;
  const float* wd = ldd + h * 132;
  float ss = 0.f, sd = 0.f;
#pragma unroll
  for (int k = 0; k < IN_F; k += 4) {
    float4 xv = *(const float4*)(xr + k);
    ss += xv.x * ws[k] + xv.y * ws[k + 1] + xv.z * ws[k + 2] + xv.w * ws[k + 3];
    sd += xv.x * wd[k] + xv.y * wd[k + 1] + xv.z * wd[k + 2] + xv.w * wd[k + 3];
  }
  al1s[gid] = ss;
  al1d[gid] = sd;
}

// ---------------------------------------------------------------- CSR build (by dst), edges = [0,E) real + [E, E+N) self loops
__global__ void k_hist(const int* __restrict__ ei, int* __restrict__ deg, int E, int Et) {
  int e = blockIdx.x * 256 + threadIdx.x;
  if (e >= Et) return;
  int dst = (e < E) ? ei[E + e] : (e - E);
  atomicAdd(&deg[dst], 1);
}

__global__ __launch_bounds__(1024) void k_scan(const int* __restrict__ deg,
                                               int* __restrict__ off,
                                               int* __restrict__ cursor, int nN) {
  __shared__ int sums[1024];
  int t = threadIdx.x;
  int v[8];
  int s = 0;
  int base = t * 8;
#pragma unroll
  for (int i = 0; i < 8; i++) {
    int idx = base + i;
    v[i] = (idx < nN) ? deg[idx] : 0;
    s += v[i];
  }
  sums[t] = s;
  __syncthreads();
  for (int d = 1; d < 1024; d <<= 1) {
    int xv = (t >= d) ? sums[t - d] : 0;
    __syncthreads();
    sums[t] += xv;
    __syncthreads();
  }
  int run = (t > 0) ? sums[t - 1] : 0;
#pragma unroll
  for (int i = 0; i < 8; i++) {
    int idx = base + i;
    if (idx < nN) { off[idx] = run; cursor[idx] = run; }
    run += v[i];
  }
  if (t == 1023) off[nN] = run;
}

__global__ void k_scatter(const int* __restrict__ ei, int* __restrict__ cursor,
                          int* __restrict__ csr, int E, int Et) {
  int e = blockIdx.x * 256 + threadIdx.x;
  if (e >= Et) return;
  int dst = (e < E) ? ei[E + e] : (e - E);
  int pos = atomicAdd(&cursor[dst], 1);
  csr[pos] = e;
}

// ---------------------------------------------------------------- attention softmax, layer 1 (thread per (node, head))
__global__ void k_att1(const int* __restrict__ ei, const int* __restrict__ off,
                       const int* __restrict__ csr, const float* __restrict__ al1s,
                       const float* __restrict__ al1d, float* __restrict__ alpha1,
                       int E, int nN) {
  int gid = blockIdx.x * 256 + threadIdx.x;
  if (gid >= nN * NH) return;
  int n = gid >> 3, h = gid & 7;
  int s0 = off[n], s1 = off[n + 1];
  float ad = al1d[n * NH + h];
  float m = -1e30f;
  for (int i = s0; i < s1; i++) {
    int eid = csr[i];
    int src = (eid < E) ? ei[eid] : (eid - E);
    float l = al1s[src * NH + h] + ad;
    l = (l > 0.f) ? l : 0.2f * l;
    m = fmaxf(m, l);
  }
  float ssum = 0.f;
  for (int i = s0; i < s1; i++) {
    int eid = csr[i];
    int src = (eid < E) ? ei[eid] : (eid - E);
    float l = al1s[src * NH + h] + ad;
    l = (l > 0.f) ? l : 0.2f * l;
    float e2 = expf(l - m);
    alpha1[(size_t)eid * NH + h] = e2;
    ssum += e2;
  }
  float inv = 1.f / (ssum + 1e-16f);
  for (int i = s0; i < s1; i++) {
    int eid = csr[i];
    alpha1[(size_t)eid * NH + h] *= inv;
  }
}

// ---------------------------------------------------------------- xa[n-c0,h,0:128] = sum_e alpha1[e,h] * x[src,:]   (64 thr/node)
__global__ __launch_bounds__(256) void k_aggx(const float* __restrict__ x,
                                              const int* __restrict__ ei,
                                              const int* __restrict__ off,
                                              const int* __restrict__ csr,
                                              const float* __restrict__ alpha1,
                                              float* __restrict__ xa, int E, int nN,
                                              int c0, int cEnd) {
  int node = c0 + blockIdx.x * 4 + (threadIdx.x >> 6);
  if (node >= cEnd) return;
  int l = threadIdx.x & 63;
  int cg = (l & 31) * 4;        // column group within 128
  int hg = (l >> 5) * 4;        // heads 0-3 or 4-7
  int s0 = off[node], s1 = off[node + 1];
  float4 a0 = {0, 0, 0, 0}, a1 = {0, 0, 0, 0}, a2 = {0, 0, 0, 0}, a3 = {0, 0, 0, 0};
  for (int i = s0; i < s1; i++) {
    int eid = csr[i];
    int src = (eid < E) ? ei[eid] : (eid - E);
    float4 xv = *(const float4*)(x + (size_t)src * IN_F + cg);
    const float* al = alpha1 + (size_t)eid * NH + hg;
    float w0 = al[0], w1 = al[1], w2 = al[2], w3 = al[3];
    a0.x += w0 * xv.x; a0.y += w0 * xv.y; a0.z += w0 * xv.z; a0.w += w0 * xv.w;
    a1.x += w1 * xv.x; a1.y += w1 * xv.y; a1.z += w1 * xv.z; a1.w += w1 * xv.w;
    a2.x += w2 * xv.x; a2.y += w2 * xv.y; a2.z += w2 * xv.z; a2.w += w2 * xv.w;
    a3.x += w3 * xv.x; a3.y += w3 * xv.y; a3.z += w3 * xv.z; a3.w += w3 * xv.w;
  }
  float* o = xa + (size_t)(node - c0) * (NH * IN_F);
  *(float4*)(o + (hg + 0) * IN_F + cg) = a0;
  *(float4*)(o + (hg + 1) * IN_F + cg) = a1;
  *(float4*)(o + (hg + 2) * IN_F + cg) = a2;
  *(float4*)(o + (hg + 3) * IN_F + cg) = a3;
}

// ---------------------------------------------------------------- tiled fp32 GEMM  C[M,N] = A@B (+bias, +act), z-batched
// EPI: 0 none, 2 bias+relu, 3 bias+elu
template <int EPI>
__global__ __launch_bounds__(256) void k_sgemm(const float* __restrict__ A,
                                               const float* __restrict__ B,
                                               const float* __restrict__ bias,
                                               float* __restrict__ C, int M, int N,
                                               int K, int lda, int ldb, int ldc,
                                               int bsA, int bsB, int bsC, int bsBias) {
  constexpr int BM = 128, BN = 64, BK = 16;
  int z = blockIdx.z;
  A += (size_t)z * bsA;
  B += (size_t)z * bsB;
  C += (size_t)z * bsC;
  if (EPI) bias += (size_t)z * bsBias;
  __shared__ float As[BK][BM + 4];
  __shared__ float Bs[BK][BN];
  const int t = threadIdx.x;
  const int tx = t & 15;   // 16 -> 4 cols each
  const int ty = t >> 4;   // 16 -> 8 rows each
  const int m0 = blockIdx.x * BM, n0 = blockIdx.y * BN;
  const int ar = t >> 2, ac = (t & 3) * 4;
  const int br = t >> 4, bc = (t & 15) * 4;
  float acc[8][4] = {};
  for (int k0 = 0; k0 < K; k0 += BK) {
    float4 va0 = *(const float4*)&A[(size_t)(m0 + ar) * lda + k0 + ac];
    float4 va1 = *(const float4*)&A[(size_t)(m0 + ar + 64) * lda + k0 + ac];
    float4 vb = *(const float4*)&B[(size_t)(k0 + br) * ldb + n0 + bc];
    __syncthreads();  // previous iter's LDS reads done
    As[ac + 0][ar] = va0.x; As[ac + 1][ar] = va0.y; As[ac + 2][ar] = va0.z; As[ac + 3][ar] = va0.w;
    As[ac + 0][ar + 64] = va1.x; As[ac + 1][ar + 64] = va1.y; As[ac + 2][ar + 64] = va1.z; As[ac + 3][ar + 64] = va1.w;
    *(float4*)&Bs[br][bc] = vb;
    __syncthreads();
#pragma unroll
    for (int k = 0; k < BK; k++) {
      float4 ra0 = *(const float4*)&As[k][ty * 8];
      float4 ra1 = *(const float4*)&As[k][ty * 8 + 4];
      float4 rb = *(const float4*)&Bs[k][tx * 4];
      float av[8] = {ra0.x, ra0.y, ra0.z, ra0.w, ra1.x, ra1.y, ra1.z, ra1.w};
      float bv[4] = {rb.x, rb.y, rb.z, rb.w};
#pragma unroll
      for (int i = 0; i < 8; i++)
#pragma unroll
        for (int j = 0; j < 4; j++) acc[i][j] += av[i] * bv[j];
    }
  }
  float4 bb = {0, 0, 0, 0};
  if (EPI) bb = *(const float4*)&bias[n0 + tx * 4];
#pragma unroll
  for (int i = 0; i < 8; i++) {
    float4 v = {acc[i][0] + bb.x, acc[i][1] + bb.y, acc[i][2] + bb.z, acc[i][3] + bb.w};
    if (EPI == 2) {
      v.x = fmaxf(v.x, 0.f); v.y = fmaxf(v.y, 0.f); v.z = fmaxf(v.z, 0.f); v.w = fmaxf(v.w, 0.f);
    }
    if (EPI == 3) {
      v.x = (v.x > 0.f) ? v.x : expm1f(v.x);
      v.y = (v.y > 0.f) ? v.y : expm1f(v.y);
      v.z = (v.z > 0.f) ? v.z : expm1f(v.z);
      v.w = (v.w > 0.f) ? v.w : expm1f(v.w);
    }
    *(float4*)&C[(size_t)(m0 + ty * 8 + i) * ldc + n0 + tx * 4] = v;
  }
}

// ---------------------------------------------------------------- al2 from g2 (wave per node)
__global__ __launch_bounds__(256) void k_al2(const float* __restrict__ g2,
                                             const float* __restrict__ a2s,
                                             const float* __restrict__ a2d,
                                             float* __restrict__ al2s,
                                             float* __restrict__ al2d, int nN) {
  int w = (blockIdx.x * 256 + threadIdx.x) >> 6;
  int lane = threadIdx.x & 63;
  if (w >= nN) return;
  const float* r = g2 + (size_t)w * HID;
  int c = lane * 4;
  float4 v0 = *(const float4*)(r + c);
  float4 v1 = *(const float4*)(r + c + 256);
  float4 s0 = *(const float4*)(a2s + c);
  float4 s1 = *(const float4*)(a2s + c + 256);
  float4 d0 = *(const float4*)(a2d + c);
  float4 d1 = *(const float4*)(a2d + c + 256);
  float ss = v0.x * s0.x + v0.y * s0.y + v0.z * s0.z + v0.w * s0.w +
             v1.x * s1.x + v1.y * s1.y + v1.z * s1.z + v1.w * s1.w;
  float sd = v0.x * d0.x + v0.y * d0.y + v0.z * d0.z + v0.w * d0.w +
             v1.x * d1.x + v1.y * d1.y + v1.z * d1.z + v1.w * d1.w;
  ss = wave_reduce(ss);
  sd = wave_reduce(sd);
  if (lane == 0) { al2s[w] = ss; al2d[w] = sd; }
}

// ---------------------------------------------------------------- attention softmax, layer 2 (thread per node)
__global__ void k_att2(const int* __restrict__ ei, const int* __restrict__ off,
                       const int* __restrict__ csr, const float* __restrict__ al2s,
                       const float* __restrict__ al2d, float* __restrict__ alpha2,
                       int E, int nN) {
  int n = blockIdx.x * 256 + threadIdx.x;
  if (n >= nN) return;
  int s0 = off[n], s1 = off[n + 1];
  float ad = al2d[n];
  float m = -1e30f;
  for (int i = s0; i < s1; i++) {
    int eid = csr[i];
    int src = (eid < E) ? ei[eid] : (eid - E);
    float l = al2s[src] + ad;
    l = (l > 0.f) ? l : 0.2f * l;
    m = fmaxf(m, l);
  }
  float ssum = 0.f;
  for (int i = s0; i < s1; i++) {
    int eid = csr[i];
    int src = (eid < E) ? ei[eid] : (eid - E);
    float l = al2s[src] + ad;
    l = (l > 0.f) ? l : 0.2f * l;
    float e2 = expf(l - m);
    alpha2[eid] = e2;
    ssum += e2;
  }
  float inv = 1.f / (ssum + 1e-16f);
  for (int i = s0; i < s1; i++) alpha2[csr[i]] *= inv;
}

// ---------------------------------------------------------------- agg2: h3[n,:] = sum_e alpha2[e]*g2[src,:] + b2  (128 thr/node)
__global__ __launch_bounds__(256) void k_agg2(const float* __restrict__ g2,
                                              const int* __restrict__ ei,
                                              const int* __restrict__ off,
                                              const int* __restrict__ csr,
                                              const float* __restrict__ alpha2,
                                              const float* __restrict__ b2,
                                              float* __restrict__ h3, int E, int nN) {
  int node = blockIdx.x * 2 + (threadIdx.x >> 7);
  if (node >= nN) return;
  int tcol = (threadIdx.x & 127) * 4;
  int s0 = off[node], s1 = off[node + 1];
  float4 acc = {0, 0, 0, 0};
  for (int i = s0; i < s1; i++) {
    int eid = csr[i];
    int src = (eid < E) ? ei[eid] : (eid - E);
    float a = alpha2[eid];
    float4 g = *(const float4*)(g2 + (size_t)src * HID + tcol);
    acc.x += a * g.x; acc.y += a * g.y; acc.z += a * g.z; acc.w += a * g.w;
  }
  float4 bb = *(const float4*)(b2 + tcol);
  acc.x += bb.x; acc.y += bb.y; acc.z += bb.z; acc.w += bb.w;
  *(float4*)(h3 + (size_t)node * HID + tcol) = acc;
}

// ---------------------------------------------------------------- final: out[p,:7] = (hf[i0]*hf[i1]) @ fc2W + fc2b  (wave/pair)
__global__ __launch_bounds__(256) void k_pairs(const float* __restrict__ hf,
                                               const int* __restrict__ te,
                                               const float* __restrict__ W,
                                               const float* __restrict__ b,
                                               float* __restrict__ out, int TEn) {
  int wid = (blockIdx.x * 256 + threadIdx.x) >> 6;
  int lane = threadIdx.x & 63;
  if (wid >= TEn) return;
  int i0 = te[wid], i1 = te[TEn + wid];
  const float* r0 = hf + (size_t)i0 * HID;
  const float* r1 = hf + (size_t)i1 * HID;
  int c = lane * 8;
  float4 p0 = *(const float4*)(r0 + c);
  float4 p1 = *(const float4*)(r0 + c + 4);
  float4 q0 = *(const float4*)(r1 + c);
  float4 q1 = *(const float4*)(r1 + c + 4);
  float pr[8] = {p0.x * q0.x, p0.y * q0.y, p0.z * q0.z, p0.w * q0.w,
                 p1.x * q1.x, p1.y * q1.y, p1.z * q1.z, p1.w * q1.w};
  float acc[7] = {};
#pragma unroll
  for (int kk = 0; kk < 8; kk++) {
    const float* wr = W + (size_t)(c + kk) * 7;
    float pv = pr[kk];
#pragma unroll
    for (int o = 0; o < 7; o++) acc[o] += pv * wr[o];
  }
#pragma unroll
  for (int o = 0; o < 7; o++) acc[o] = wave_reduce(acc[o]);
  if (lane == 0) {
#pragma unroll
    for (int o = 0; o < 7; o++) out[(size_t)wid * 7 + o] = acc[o] + b[o];
  }
}

// ================================================================ launcher
extern "C" void kernel_launch(void* const* d_in, const int* in_sizes, int n_in,
                              void* d_out, int out_size, void* d_ws, size_t ws_size,
                              hipStream_t stream) {
  const float* x = (const float*)d_in[0];
  const int* ei = (const int*)d_in[1];
  const int* te = (const int*)d_in[2];
  const float* W1 = (const float*)d_in[3];
  const float* a1s = (const float*)d_in[4];
  const float* a1d = (const float*)d_in[5];
  const float* b1 = (const float*)d_in[6];
  const float* W2 = (const float*)d_in[7];
  const float* a2s = (const float*)d_in[8];
  const float* a2d = (const float*)d_in[9];
  const float* b2 = (const float*)d_in[10];
  const float* l1W = (const float*)d_in[11];
  const float* l1b = (const float*)d_in[12];
  const float* f2W = (const float*)d_in[13];
  const float* f2b = (const float*)d_in[14];
  float* out = (float*)d_out;

  const int nN = in_sizes[0] / IN_F;   // 8192
  const int E = in_sizes[1] / 2;       // 65536
  const int TEn = in_sizes[2] / 2;     // 100000
  const int Et = E + nN;               // + self loops

  // ---- adaptive workspace plan: chunk rows of {aggx -> GEMM1 -> GEMM2}
  // so the footprint fits ws_size (g2[n] depends only on h2[n] -> row-chunkable).
  const size_t g2B = (size_t)nN * HID * 4;                       // persistent g2
  const size_t smallB = 2 * (size_t)NH * IN_F * 4                // wa1s/d
                      + 2 * (size_t)nN * NH * 4                  // al1s/d
                      + 2 * (size_t)nN * 4                       // al2s/d
                      + (size_t)Et * NH * 4 + (size_t)Et * 4     // alpha1/2
                      + 3 * (size_t)nN * 4 + ((size_t)nN + 1) * 4
                      + (size_t)Et * 4;                          // deg/off/cursor/csr
  int CH = nN;  // rows per chunk (multiple of 128)
  for (;;) {
    size_t regA = (size_t)CH * NH * IN_F * 4;                    // xa chunk
    if (regA < (size_t)nN * HID * 4) regA = (size_t)nN * HID * 4;     // reused as h3
    size_t regB = (size_t)CH * NH * HID * 4;                     // h2 chunk
    if (regB < (size_t)nN * HID * 4) regB = (size_t)nN * HID * 4;     // reused as hf
    size_t tot = regA + regB + g2B + smallB + 16 * 256;          // + align slop
    if (tot <= ws_size || CH <= 128) break;
    CH >>= 1;
  }
  const size_t regASz = ((size_t)CH * NH * IN_F * 4 > (size_t)nN * HID * 4)
                            ? (size_t)CH * NH * IN_F * 4 : (size_t)nN * HID * 4;
  const size_t regBSz = ((size_t)CH * NH * HID * 4 > (size_t)nN * HID * 4)
                            ? (size_t)CH * NH * HID * 4 : (size_t)nN * HID * 4;

  char* p = (char*)d_ws;
  auto alloc = [&](size_t bytes) -> char* {
    char* r = p;
    p += (bytes + 255) & ~(size_t)255;
    return r;
  };
  float* regA = (float*)alloc(regASz);   // xa chunk, then h3
  float* regB = (float*)alloc(regBSz);   // h2 chunk, then hf
  float* g2 = (float*)alloc(g2B);
  float* xa = regA;
  float* h2 = regB;
  float* h3 = regA;
  float* hf = regB;
  float* wa1s = (float*)alloc(NH * IN_F * 4);
  float* wa1d = (float*)alloc(NH * IN_F * 4);
  float* al1s = (float*)alloc((size_t)nN * NH * 4);
  float* al1d = (float*)alloc((size_t)nN * NH * 4);
  float* al2s = (float*)alloc((size_t)nN * 4);
  float* al2d = (float*)alloc((size_t)nN * 4);
  float* alpha1 = (float*)alloc((size_t)Et * NH * 4);
  float* alpha2 = (float*)alloc((size_t)Et * 4);
  int* deg = (int*)alloc((size_t)nN * 4);
  int* off = (int*)alloc((size_t)(nN + 1) * 4);
  int* cursor = (int*)alloc((size_t)nN * 4);
  int* csr = (int*)alloc((size_t)Et * 4);
  (void)n_in; (void)out_size;

  hipMemsetAsync(deg, 0, (size_t)nN * 4, stream);

  // attention prelims (no h1 materialization)
  k_wa1<<<(NH * IN_F * 64 + 255) / 256, 256, 0, stream>>>(W1, a1s, a1d, wa1s, wa1d);
  k_al1<<<(nN * NH + 255) / 256, 256, 0, stream>>>(x, wa1s, wa1d, al1s, al1d, nN);

  // CSR by dst
  k_hist<<<(Et + 255) / 256, 256, 0, stream>>>(ei, deg, E, Et);
  k_scan<<<1, 1024, 0, stream>>>(deg, off, cursor, nN);
  k_scatter<<<(Et + 255) / 256, 256, 0, stream>>>(ei, cursor, csr, E, Et);

  // layer-1 softmax
  k_att1<<<(nN * NH + 255) / 256, 256, 0, stream>>>(ei, off, csr, al1s, al1d, alpha1, E, nN);

  // chunked: aggx -> GEMM1 (bias+elu) -> GEMM2
  for (int c0 = 0; c0 < nN; c0 += CH) {
    int rows = (nN - c0 < CH) ? (nN - c0) : CH;
    k_aggx<<<(rows + 3) / 4, 256, 0, stream>>>(x, ei, off, csr, alpha1, xa, E, nN,
                                               c0, c0 + rows);
    {  // h2[r, h*512+c] = elu( xa[r,h,:] @ W1[:, h*512+c] + b1 )
      dim3 g(rows / 128, HID / 64, NH);
      k_sgemm<3><<<g, 256, 0, stream>>>(xa, W1, b1, h2, rows, HID, IN_F,
                                        NH * IN_F, NH * HID, NH * HID,
                                        IN_F, HID, HID, HID);
    }
    {  // g2 rows = h2 @ W2
      dim3 g(rows / 128, HID / 64, 1);
      k_sgemm<0><<<g, 256, 0, stream>>>(h2, W2, nullptr, g2 + (size_t)c0 * HID,
                                        rows, HID, NH * HID,
                                        NH * HID, HID, HID, 0, 0, 0, 0);
    }
  }

  // layer 2 attention + aggregation
  k_al2<<<(nN * 64 + 255) / 256, 256, 0, stream>>>(g2, a2s, a2d, al2s, al2d, nN);
  k_att2<<<(nN + 255) / 256, 256, 0, stream>>>(ei, off, csr, al2s, al2d, alpha2, E, nN);
  k_agg2<<<(nN + 1) / 2, 256, 0, stream>>>(g2, ei, off, csr, alpha2, b2, h3, E, nN);

  // lin1 + relu
  {
    dim3 g(nN / 128, HID / 64, 1);
    k_sgemm<2><<<g, 256, 0, stream>>>(h3, l1W, l1b, hf, nN, HID, HID,
                                      HID, HID, HID, 0, 0, 0, 0);
  }

  // pair scoring
  k_pairs<<<(TEn * 64 + 255) / 256, 256, 0, stream>>>(hf, te, f2W, f2b, out, TEn);
}

// Round 12
// 647.076 us; speedup vs baseline: 1.5420x; 1.5420x over previous
//
#include <hip/hip_runtime.h>
#include <hip/hip_bf16.h>
#include <math.h>

#define IN_F 128
#define HID 512
#define NH 8

typedef __attribute__((ext_vector_type(8))) short bf16x8;   // 8 bf16 in 4 VGPRs
typedef __attribute__((ext_vector_type(4))) float f32x4;
typedef __attribute__((ext_vector_type(4))) unsigned short u16x4;

// ---------------------------------------------------------------- utilities

__device__ __forceinline__ float wave_reduce(float v) {
#pragma unroll
  for (int s = 32; s > 0; s >>= 1) v += __shfl_down(v, s, 64);
  return v;
}

__device__ __forceinline__ unsigned short f2bf(float f) {
  __hip_bfloat16 b = __float2bfloat16(f);
  return *reinterpret_cast<unsigned short*>(&b);
}
__device__ __forceinline__ float bf2f(unsigned short u) {
  __hip_bfloat16 b = *reinterpret_cast<__hip_bfloat16*>(&u);
  return __bfloat162float(b);
}

// ---------------------------------------------------------------- wa1 = per-head W1 @ a1
__global__ __launch_bounds__(256) void k_wa1(const float* __restrict__ W1,
                                             const float* __restrict__ a1s,
                                             const float* __restrict__ a1d,
                                             float* __restrict__ wa1s,
                                             float* __restrict__ wa1d) {
  int w = (blockIdx.x * blockDim.x + threadIdx.x) >> 6;
  int lane = threadIdx.x & 63;
  if (w >= NH * IN_F) return;
  int h = w >> 7;
  int k = w & 127;
  const float* wrow = W1 + (size_t)k * (NH * HID) + h * HID;
  const float* as = a1s + h * HID;
  const float* ad = a1d + h * HID;
  int c = lane * 8;
  float4 w0 = *(const float4*)(wrow + c);
  float4 w1 = *(const float4*)(wrow + c + 4);
  float4 s0 = *(const float4*)(as + c);
  float4 s1 = *(const float4*)(as + c + 4);
  float4 d0 = *(const float4*)(ad + c);
  float4 d1 = *(const float4*)(ad + c + 4);
  float ss = w0.x * s0.x + w0.y * s0.y + w0.z * s0.z + w0.w * s0.w +
             w1.x * s1.x + w1.y * s1.y + w1.z * s1.z + w1.w * s1.w;
  float sd = w0.x * d0.x + w0.y * d0.y + w0.z * d0.z + w0.w * d0.w +
             w1.x * d1.x + w1.y * d1.y + w1.z * d1.z + w1.w * d1.w;
  ss = wave_reduce(ss);
  sd = wave_reduce(sd);
  if (lane == 0) { wa1s[h * IN_F + k] = ss; wa1d[h * IN_F + k] = sd; }
}

// ---------------------------------------------------------------- al1 = x @ wa1^T
__global__ __launch_bounds__(256) void k_al1(const float* __restrict__ x,
                                             const float* __restrict__ wa1s,
                                             const float* __restrict__ wa1d,
                                             float* __restrict__ al1s,
                                             float* __restrict__ al1d, int nN) {
  __shared__ float ls[NH * 132];
  __shared__ float ldd[NH * 132];
  for (int i = threadIdx.x; i < NH * IN_F; i += 256) {
    int h = i >> 7, k = i & 127;
    ls[h * 132 + k] = wa1s[i];
    ldd[h * 132 + k] = wa1d[i];
  }
  __syncthreads();
  int gid = blockIdx.x * 256 + threadIdx.x;
  if (gid >= nN * NH) return;
  int n = gid >> 3, h = gid & 7;
  const float* xr = x + (size_t)n * IN_F;
  const float* ws = ls + h * 132;
  const float* wd = ldd + h * 132;
  float ss = 0.f, sd = 0.f;
#pragma unroll
  for (int k = 0; k < IN_F; k += 4) {
    float4 xv = *(const float4*)(xr + k);
    ss += xv.x * ws[k] + xv.y * ws[k + 1] + xv.z * ws[k + 2] + xv.w * ws[k + 3];
    sd += xv.x * wd[k] + xv.y * wd[k + 1] + xv.z * wd[k + 2] + xv.w * wd[k + 3];
  }
  al1s[gid] = ss;
  al1d[gid] = sd;
}

// ---------------------------------------------------------------- CSR build
__global__ void k_hist(const int* __restrict__ ei, int* __restrict__ deg, int E, int Et) {
  int e = blockIdx.x * 256 + threadIdx.x;
  if (e >= Et) return;
  int dst = (e < E) ? ei[E + e] : (e - E);
  atomicAdd(&deg[dst], 1);
}

__global__ __launch_bounds__(1024) void k_scan(const int* __restrict__ deg,
                                               int* __restrict__ off,
                                               int* __restrict__ cursor, int nN) {
  __shared__ int sums[1024];
  int t = threadIdx.x;
  int v[8];
  int s = 0;
  int base = t * 8;
#pragma unroll
  for (int i = 0; i < 8; i++) {
    int idx = base + i;
    v[i] = (idx < nN) ? deg[idx] : 0;
    s += v[i];
  }
  sums[t] = s;
  __syncthreads();
  for (int d = 1; d < 1024; d <<= 1) {
    int xv = (t >= d) ? sums[t - d] : 0;
    __syncthreads();
    sums[t] += xv;
    __syncthreads();
  }
  int run = (t > 0) ? sums[t - 1] : 0;
#pragma unroll
  for (int i = 0; i < 8; i++) {
    int idx = base + i;
    if (idx < nN) { off[idx] = run; cursor[idx] = run; }
    run += v[i];
  }
  if (t == 1023) off[nN] = run;
}

__global__ void k_scatter(const int* __restrict__ ei, int* __restrict__ cursor,
                          int* __restrict__ csr, int E, int Et) {
  int e = blockIdx.x * 256 + threadIdx.x;
  if (e >= Et) return;
  int dst = (e < E) ? ei[E + e] : (e - E);
  int pos = atomicAdd(&cursor[dst], 1);
  csr[pos] = e;
}

// ---------------------------------------------------------------- attention softmax, layer 1
__global__ void k_att1(const int* __restrict__ ei, const int* __restrict__ off,
                       const int* __restrict__ csr, const float* __restrict__ al1s,
                       const float* __restrict__ al1d, float* __restrict__ alpha1,
                       int E, int nN) {
  int gid = blockIdx.x * 256 + threadIdx.x;
  if (gid >= nN * NH) return;
  int n = gid >> 3, h = gid & 7;
  int s0 = off[n], s1 = off[n + 1];
  float ad = al1d[n * NH + h];
  float m = -1e30f;
  for (int i = s0; i < s1; i++) {
    int eid = csr[i];
    int src = (eid < E) ? ei[eid] : (eid - E);
    float l = al1s[src * NH + h] + ad;
    l = (l > 0.f) ? l : 0.2f * l;
    m = fmaxf(m, l);
  }
  float ssum = 0.f;
  for (int i = s0; i < s1; i++) {
    int eid = csr[i];
    int src = (eid < E) ? ei[eid] : (eid - E);
    float l = al1s[src * NH + h] + ad;
    l = (l > 0.f) ? l : 0.2f * l;
    float e2 = expf(l - m);
    alpha1[(size_t)eid * NH + h] = e2;
    ssum += e2;
  }
  float inv = 1.f / (ssum + 1e-16f);
  for (int i = s0; i < s1; i++) {
    int eid = csr[i];
    alpha1[(size_t)eid * NH + h] *= inv;
  }
}

// ---------------------------------------------------------------- xa aggregation
__global__ __launch_bounds__(256) void k_aggx(const float* __restrict__ x,
                                              const int* __restrict__ ei,
                                              const int* __restrict__ off,
                                              const int* __restrict__ csr,
                                              const float* __restrict__ alpha1,
                                              float* __restrict__ xa, int E, int nN,
                                              int c0, int cEnd) {
  int node = c0 + blockIdx.x * 4 + (threadIdx.x >> 6);
  if (node >= cEnd) return;
  int l = threadIdx.x & 63;
  int cg = (l & 31) * 4;
  int hg = (l >> 5) * 4;
  int s0 = off[node], s1 = off[node + 1];
  float4 a0 = {0, 0, 0, 0}, a1 = {0, 0, 0, 0}, a2 = {0, 0, 0, 0}, a3 = {0, 0, 0, 0};
  for (int i = s0; i < s1; i++) {
    int eid = csr[i];
    int src = (eid < E) ? ei[eid] : (eid - E);
    float4 xv = *(const float4*)(x + (size_t)src * IN_F + cg);
    const float* al = alpha1 + (size_t)eid * NH + hg;
    float w0 = al[0], w1 = al[1], w2 = al[2], w3 = al[3];
    a0.x += w0 * xv.x; a0.y += w0 * xv.y; a0.z += w0 * xv.z; a0.w += w0 * xv.w;
    a1.x += w1 * xv.x; a1.y += w1 * xv.y; a1.z += w1 * xv.z; a1.w += w1 * xv.w;
    a2.x += w2 * xv.x; a2.y += w2 * xv.y; a2.z += w2 * xv.z; a2.w += w2 * xv.w;
    a3.x += w3 * xv.x; a3.y += w3 * xv.y; a3.z += w3 * xv.z; a3.w += w3 * xv.w;
  }
  float* o = xa + (size_t)(node - c0) * (NH * IN_F);
  *(float4*)(o + (hg + 0) * IN_F + cg) = a0;
  *(float4*)(o + (hg + 1) * IN_F + cg) = a1;
  *(float4*)(o + (hg + 2) * IN_F + cg) = a2;
  *(float4*)(o + (hg + 3) * IN_F + cg) = a3;
}

// ---------------------------------------------------------------- tiled fp32 GEMM
// EPI: 0 none, 2 bias+relu, 3 bias+elu with SPLIT-BF16 output (Ch/Cl, no fp32 C)
template <int EPI>
__global__ __launch_bounds__(256) void k_sgemm(const float* __restrict__ A,
                                               const float* __restrict__ B,
                                               const float* __restrict__ bias,
                                               float* __restrict__ C, int M, int N,
                                               int K, int lda, int ldb, int ldc,
                                               int bsA, int bsB, int bsC, int bsBias,
                                               unsigned short* __restrict__ Ch,
                                               unsigned short* __restrict__ Cl) {
  constexpr int BM = 128, BN = 64, BK = 16;
  int z = blockIdx.z;
  A += (size_t)z * bsA;
  B += (size_t)z * bsB;
  if (EPI != 3) C += (size_t)z * bsC;
  if (EPI == 3) { Ch += (size_t)z * bsC; Cl += (size_t)z * bsC; }
  if (EPI) bias += (size_t)z * bsBias;
  __shared__ float As[BK][BM + 4];
  __shared__ float Bs[BK][BN];
  const int t = threadIdx.x;
  const int tx = t & 15;
  const int ty = t >> 4;
  const int m0 = blockIdx.x * BM, n0 = blockIdx.y * BN;
  const int ar = t >> 2, ac = (t & 3) * 4;
  const int br = t >> 4, bc = (t & 15) * 4;
  float acc[8][4] = {};
  for (int k0 = 0; k0 < K; k0 += BK) {
    float4 va0 = *(const float4*)&A[(size_t)(m0 + ar) * lda + k0 + ac];
    float4 va1 = *(const float4*)&A[(size_t)(m0 + ar + 64) * lda + k0 + ac];
    float4 vb = *(const float4*)&B[(size_t)(k0 + br) * ldb + n0 + bc];
    __syncthreads();
    As[ac + 0][ar] = va0.x; As[ac + 1][ar] = va0.y; As[ac + 2][ar] = va0.z; As[ac + 3][ar] = va0.w;
    As[ac + 0][ar + 64] = va1.x; As[ac + 1][ar + 64] = va1.y; As[ac + 2][ar + 64] = va1.z; As[ac + 3][ar + 64] = va1.w;
    *(float4*)&Bs[br][bc] = vb;
    __syncthreads();
#pragma unroll
    for (int k = 0; k < BK; k++) {
      float4 ra0 = *(const float4*)&As[k][ty * 8];
      float4 ra1 = *(const float4*)&As[k][ty * 8 + 4];
      float4 rb = *(const float4*)&Bs[k][tx * 4];
      float av[8] = {ra0.x, ra0.y, ra0.z, ra0.w, ra1.x, ra1.y, ra1.z, ra1.w};
      float bv[4] = {rb.x, rb.y, rb.z, rb.w};
#pragma unroll
      for (int i = 0; i < 8; i++)
#pragma unroll
        for (int j = 0; j < 4; j++) acc[i][j] += av[i] * bv[j];
    }
  }
  float4 bb = {0, 0, 0, 0};
  if (EPI) bb = *(const float4*)&bias[n0 + tx * 4];
#pragma unroll
  for (int i = 0; i < 8; i++) {
    float4 v = {acc[i][0] + bb.x, acc[i][1] + bb.y, acc[i][2] + bb.z, acc[i][3] + bb.w};
    if (EPI == 2) {
      v.x = fmaxf(v.x, 0.f); v.y = fmaxf(v.y, 0.f); v.z = fmaxf(v.z, 0.f); v.w = fmaxf(v.w, 0.f);
    }
    size_t cidx = (size_t)(m0 + ty * 8 + i) * ldc + n0 + tx * 4;
    if (EPI == 3) {
      v.x = (v.x > 0.f) ? v.x : expm1f(v.x);
      v.y = (v.y > 0.f) ? v.y : expm1f(v.y);
      v.z = (v.z > 0.f) ? v.z : expm1f(v.z);
      v.w = (v.w > 0.f) ? v.w : expm1f(v.w);
      u16x4 hv, lv;
      hv.x = f2bf(v.x); lv.x = f2bf(v.x - bf2f(hv.x));
      hv.y = f2bf(v.y); lv.y = f2bf(v.y - bf2f(hv.y));
      hv.z = f2bf(v.z); lv.z = f2bf(v.z - bf2f(hv.z));
      hv.w = f2bf(v.w); lv.w = f2bf(v.w - bf2f(hv.w));
      *(u16x4*)&Ch[cidx] = hv;
      *(u16x4*)&Cl[cidx] = lv;
    } else {
      *(float4*)&C[cidx] = v;
    }
  }
}

// ---------------------------------------------------------------- W2 -> transposed hi/lo bf16 [N][K]
__global__ __launch_bounds__(256) void k_cvtW2(const float* __restrict__ W2,
                                               unsigned short* __restrict__ Wth,
                                               unsigned short* __restrict__ Wtl,
                                               int N, int K) {
  int gid = blockIdx.x * 256 + threadIdx.x;
  if (gid >= (K >> 3) * N) return;
  int n = gid % N;
  int k0 = (gid / N) * 8;
#pragma unroll
  for (int j = 0; j < 8; j++) {
    float f = W2[(size_t)(k0 + j) * N + n];   // coalesced across n
    unsigned short h = f2bf(f);
    unsigned short l = f2bf(f - bf2f(h));
    Wth[(size_t)n * K + k0 + j] = h;
    Wtl[(size_t)n * K + k0 + j] = l;
  }
}

// ---------------------------------------------------------------- GEMM2 via split-bf16 MFMA
// C[M,N] = (Ah+Al) @ (Bh+Bl)^T-stored, dropping Al*Bl.  A: [M][K] bf16 pair, Bt: [N][K] bf16 pair.
// Tile 128x64, BK=32, 4 waves; wave (wm,wn) owns 64x32; frags 4(M)x2(N) of 16x16.
// MFMA mfma_f32_16x16x32_bf16 layouts (m89/m91-verified family):
//   A: lane holds A[l&15][(l>>4)*8+j]; B: lane holds B[(l>>4)*8+j][l&15] (via [col][k] LDS);
//   D: row=(l>>4)*4+q, col=l&15.
__global__ __launch_bounds__(256) void k_gemm2_mfma(const unsigned short* __restrict__ Ah,
                                                    const unsigned short* __restrict__ Al,
                                                    const unsigned short* __restrict__ Bth,
                                                    const unsigned short* __restrict__ Btl,
                                                    float* __restrict__ C,
                                                    int M, int N, int K) {
  __shared__ unsigned short Ash[128 * 40];  // [row][k] pad 40 (80B rows -> ~2-way banks)
  __shared__ unsigned short Asl[128 * 40];
  __shared__ unsigned short Bsh[64 * 40];   // [col][k]
  __shared__ unsigned short Bsl[64 * 40];
  const int t = threadIdx.x;
  const int m0 = blockIdx.x * 128, n0 = blockIdx.y * 64;
  const int lane = t & 63, w = t >> 6;
  const int wm = w >> 1, wn = w & 1;
  const int l16 = lane & 15, lk = (lane >> 4) * 8;
  // staging map: 8 bf16 per thread per region
  const int ar0 = t >> 2, ak0 = (t & 3) * 8;            // A rows 0..63
  const int ar1 = 64 + (t >> 2), ak1 = (t & 3) * 8;     // A rows 64..127
  const int bc = t >> 2, bk = (t & 3) * 8;              // B cols 0..63

  f32x4 acc[4][2] = {};
  const int NK = K >> 5;

  bf16x8 rah0, rah1, ral0, ral1, rbh, rbl;
  {
    rah0 = *(const bf16x8*)&Ah[(size_t)(m0 + ar0) * K + ak0];
    rah1 = *(const bf16x8*)&Ah[(size_t)(m0 + ar1) * K + ak1];
    ral0 = *(const bf16x8*)&Al[(size_t)(m0 + ar0) * K + ak0];
    ral1 = *(const bf16x8*)&Al[(size_t)(m0 + ar1) * K + ak1];
    rbh  = *(const bf16x8*)&Bth[(size_t)(n0 + bc) * K + bk];
    rbl  = *(const bf16x8*)&Btl[(size_t)(n0 + bc) * K + bk];
  }
  for (int kt = 0; kt < NK; ++kt) {
    __syncthreads();
    *(bf16x8*)&Ash[ar0 * 40 + ak0] = rah0;
    *(bf16x8*)&Ash[ar1 * 40 + ak1] = rah1;
    *(bf16x8*)&Asl[ar0 * 40 + ak0] = ral0;
    *(bf16x8*)&Asl[ar1 * 40 + ak1] = ral1;
    *(bf16x8*)&Bsh[bc * 40 + bk] = rbh;
    *(bf16x8*)&Bsl[bc * 40 + bk] = rbl;
    __syncthreads();
    if (kt + 1 < NK) {  // prefetch next tile; HBM latency hides under ds_read+MFMA
      int k0 = (kt + 1) << 5;
      rah0 = *(const bf16x8*)&Ah[(size_t)(m0 + ar0) * K + k0 + ak0];
      rah1 = *(const bf16x8*)&Ah[(size_t)(m0 + ar1) * K + k0 + ak1];
      ral0 = *(const bf16x8*)&Al[(size_t)(m0 + ar0) * K + k0 + ak0];
      ral1 = *(const bf16x8*)&Al[(size_t)(m0 + ar1) * K + k0 + ak1];
      rbh  = *(const bf16x8*)&Bth[(size_t)(n0 + bc) * K + k0 + bk];
      rbl  = *(const bf16x8*)&Btl[(size_t)(n0 + bc) * K + k0 + bk];
    }
    bf16x8 fah[4], fal[4], fbh[2], fbl[2];
#pragma unroll
    for (int fm = 0; fm < 4; fm++) {
      int r = (wm * 64 + fm * 16 + l16) * 40 + lk;
      fah[fm] = *(const bf16x8*)&Ash[r];
      fal[fm] = *(const bf16x8*)&Asl[r];
    }
#pragma unroll
    for (int fn = 0; fn < 2; fn++) {
      int r = (wn * 32 + fn * 16 + l16) * 40 + lk;
      fbh[fn] = *(const bf16x8*)&Bsh[r];
      fbl[fn] = *(const bf16x8*)&Bsl[r];
    }
    // hh, hl, lh groups (8 independent accs within each group)
#pragma unroll
    for (int fm = 0; fm < 4; fm++)
#pragma unroll
      for (int fn = 0; fn < 2; fn++)
        acc[fm][fn] = __builtin_amdgcn_mfma_f32_16x16x32_bf16(fah[fm], fbh[fn], acc[fm][fn], 0, 0, 0);
#pragma unroll
    for (int fm = 0; fm < 4; fm++)
#pragma unroll
      for (int fn = 0; fn < 2; fn++)
        acc[fm][fn] = __builtin_amdgcn_mfma_f32_16x16x32_bf16(fah[fm], fbl[fn], acc[fm][fn], 0, 0, 0);
#pragma unroll
    for (int fm = 0; fm < 4; fm++)
#pragma unroll
      for (int fn = 0; fn < 2; fn++)
        acc[fm][fn] = __builtin_amdgcn_mfma_f32_16x16x32_bf16(fal[fm], fbh[fn], acc[fm][fn], 0, 0, 0);
  }
#pragma unroll
  for (int fm = 0; fm < 4; fm++)
#pragma unroll
    for (int fn = 0; fn < 2; fn++) {
      int row = m0 + wm * 64 + fm * 16 + (lane >> 4) * 4;
      int col = n0 + wn * 32 + fn * 16 + l16;
#pragma unroll
      for (int q = 0; q < 4; q++)
        C[(size_t)(row + q) * N + col] = acc[fm][fn][q];
    }
}

// ---------------------------------------------------------------- al2 from g2
__global__ __launch_bounds__(256) void k_al2(const float* __restrict__ g2,
                                             const float* __restrict__ a2s,
                                             const float* __restrict__ a2d,
                                             float* __restrict__ al2s,
                                             float* __restrict__ al2d, int nN) {
  int w = (blockIdx.x * 256 + threadIdx.x) >> 6;
  int lane = threadIdx.x & 63;
  if (w >= nN) return;
  const float* r = g2 + (size_t)w * HID;
  int c = lane * 4;
  float4 v0 = *(const float4*)(r + c);
  float4 v1 = *(const float4*)(r + c + 256);
  float4 s0 = *(const float4*)(a2s + c);
  float4 s1 = *(const float4*)(a2s + c + 256);
  float4 d0 = *(const float4*)(a2d + c);
  float4 d1 = *(const float4*)(a2d + c + 256);
  float ss = v0.x * s0.x + v0.y * s0.y + v0.z * s0.z + v0.w * s0.w +
             v1.x * s1.x + v1.y * s1.y + v1.z * s1.z + v1.w * s1.w;
  float sd = v0.x * d0.x + v0.y * d0.y + v0.z * d0.z + v0.w * d0.w +
             v1.x * d1.x + v1.y * d1.y + v1.z * d1.z + v1.w * d1.w;
  ss = wave_reduce(ss);
  sd = wave_reduce(sd);
  if (lane == 0) { al2s[w] = ss; al2d[w] = sd; }
}

// ---------------------------------------------------------------- attention softmax, layer 2
__global__ void k_att2(const int* __restrict__ ei, const int* __restrict__ off,
                       const int* __restrict__ csr, const float* __restrict__ al2s,
                       const float* __restrict__ al2d, float* __restrict__ alpha2,
                       int E, int nN) {
  int n = blockIdx.x * 256 + threadIdx.x;
  if (n >= nN) return;
  int s0 = off[n], s1 = off[n + 1];
  float ad = al2d[n];
  float m = -1e30f;
  for (int i = s0; i < s1; i++) {
    int eid = csr[i];
    int src = (eid < E) ? ei[eid] : (eid - E);
    float l = al2s[src] + ad;
    l = (l > 0.f) ? l : 0.2f * l;
    m = fmaxf(m, l);
  }
  float ssum = 0.f;
  for (int i = s0; i < s1; i++) {
    int eid = csr[i];
    int src = (eid < E) ? ei[eid] : (eid - E);
    float l = al2s[src] + ad;
    l = (l > 0.f) ? l : 0.2f * l;
    float e2 = expf(l - m);
    alpha2[eid] = e2;
    ssum += e2;
  }
  float inv = 1.f / (ssum + 1e-16f);
  for (int i = s0; i < s1; i++) alpha2[csr[i]] *= inv;
}

// ---------------------------------------------------------------- agg2
__global__ __launch_bounds__(256) void k_agg2(const float* __restrict__ g2,
                                              const int* __restrict__ ei,
                                              const int* __restrict__ off,
                                              const int* __restrict__ csr,
                                              const float* __restrict__ alpha2,
                                              const float* __restrict__ b2,
                                              float* __restrict__ h3, int E, int nN) {
  int node = blockIdx.x * 2 + (threadIdx.x >> 7);
  if (node >= nN) return;
  int tcol = (threadIdx.x & 127) * 4;
  int s0 = off[node], s1 = off[node + 1];
  float4 acc = {0, 0, 0, 0};
  for (int i = s0; i < s1; i++) {
    int eid = csr[i];
    int src = (eid < E) ? ei[eid] : (eid - E);
    float a = alpha2[eid];
    float4 g = *(const float4*)(g2 + (size_t)src * HID + tcol);
    acc.x += a * g.x; acc.y += a * g.y; acc.z += a * g.z; acc.w += a * g.w;
  }
  float4 bb = *(const float4*)(b2 + tcol);
  acc.x += bb.x; acc.y += bb.y; acc.z += bb.z; acc.w += bb.w;
  *(float4*)(h3 + (size_t)node * HID + tcol) = acc;
}

// ---------------------------------------------------------------- pair scoring
__global__ __launch_bounds__(256) void k_pairs(const float* __restrict__ hf,
                                               const int* __restrict__ te,
                                               const float* __restrict__ W,
                                               const float* __restrict__ b,
                                               float* __restrict__ out, int TEn) {
  int wid = (blockIdx.x * 256 + threadIdx.x) >> 6;
  int lane = threadIdx.x & 63;
  if (wid >= TEn) return;
  int i0 = te[wid], i1 = te[TEn + wid];
  const float* r0 = hf + (size_t)i0 * HID;
  const float* r1 = hf + (size_t)i1 * HID;
  int c = lane * 8;
  float4 p0 = *(const float4*)(r0 + c);
  float4 p1 = *(const float4*)(r0 + c + 4);
  float4 q0 = *(const float4*)(r1 + c);
  float4 q1 = *(const float4*)(r1 + c + 4);
  float pr[8] = {p0.x * q0.x, p0.y * q0.y, p0.z * q0.z, p0.w * q0.w,
                 p1.x * q1.x, p1.y * q1.y, p1.z * q1.z, p1.w * q1.w};
  float acc[7] = {};
#pragma unroll
  for (int kk = 0; kk < 8; kk++) {
    const float* wr = W + (size_t)(c + kk) * 7;
    float pv = pr[kk];
#pragma unroll
    for (int o = 0; o < 7; o++) acc[o] += pv * wr[o];
  }
#pragma unroll
  for (int o = 0; o < 7; o++) acc[o] = wave_reduce(acc[o]);
  if (lane == 0) {
#pragma unroll
    for (int o = 0; o < 7; o++) out[(size_t)wid * 7 + o] = acc[o] + b[o];
  }
}

// ================================================================ launcher
extern "C" void kernel_launch(void* const* d_in, const int* in_sizes, int n_in,
                              void* d_out, int out_size, void* d_ws, size_t ws_size,
                              hipStream_t stream) {
  const float* x = (const float*)d_in[0];
  const int* ei = (const int*)d_in[1];
  const int* te = (const int*)d_in[2];
  const float* W1 = (const float*)d_in[3];
  const float* a1s = (const float*)d_in[4];
  const float* a1d = (const float*)d_in[5];
  const float* b1 = (const float*)d_in[6];
  const float* W2 = (const float*)d_in[7];
  const float* a2s = (const float*)d_in[8];
  const float* a2d = (const float*)d_in[9];
  const float* b2 = (const float*)d_in[10];
  const float* l1W = (const float*)d_in[11];
  const float* l1b = (const float*)d_in[12];
  const float* f2W = (const float*)d_in[13];
  const float* f2b = (const float*)d_in[14];
  float* out = (float*)d_out;

  const int nN = in_sizes[0] / IN_F;   // 8192
  const int E = in_sizes[1] / 2;       // 65536
  const int TEn = in_sizes[2] / 2;     // 100000
  const int Et = E + nN;
  const int K2 = NH * HID;             // 4096

  // ---- adaptive workspace plan (chunk {aggx -> GEMM1 -> GEMM2-MFMA} rows)
  const size_t g2B = (size_t)nN * HID * 4;
  const size_t smallB = 2 * (size_t)NH * IN_F * 4
                      + 2 * (size_t)nN * NH * 4
                      + 2 * (size_t)nN * 4
                      + (size_t)Et * NH * 4 + (size_t)Et * 4
                      + 3 * (size_t)nN * 4 + ((size_t)nN + 1) * 4
                      + (size_t)Et * 4
                      + 2 * (size_t)HID * K2 * 2;                // W2th/W2tl bf16
  int CH = nN;
  for (;;) {
    size_t regA = (size_t)CH * NH * IN_F * 4;                    // xa chunk (reused as h3)
    if (regA < (size_t)nN * HID * 4) regA = (size_t)nN * HID * 4;
    size_t regB = (size_t)CH * K2 * 4;                           // h2h+h2l bf16 pair (== fp32 bytes), reused as hf
    if (regB < (size_t)nN * HID * 4) regB = (size_t)nN * HID * 4;
    size_t tot = regA + regB + g2B + smallB + 24 * 256;
    if (tot <= ws_size || CH <= 128) break;
    CH >>= 1;
  }
  const size_t regASz = ((size_t)CH * NH * IN_F * 4 > (size_t)nN * HID * 4)
                            ? (size_t)CH * NH * IN_F * 4 : (size_t)nN * HID * 4;
  const size_t regBSz = ((size_t)CH * K2 * 4 > (size_t)nN * HID * 4)
                            ? (size_t)CH * K2 * 4 : (size_t)nN * HID * 4;

  char* p = (char*)d_ws;
  auto alloc = [&](size_t bytes) -> char* {
    char* r = p;
    p += (bytes + 255) & ~(size_t)255;
    return r;
  };
  float* regA = (float*)alloc(regASz);      // xa chunk, then h3
  char* regB = alloc(regBSz);               // h2h|h2l bf16 chunk, then hf
  float* g2 = (float*)alloc(g2B);
  float* xa = regA;
  float* h3 = regA;
  unsigned short* h2h = (unsigned short*)regB;
  unsigned short* h2l = h2h + (size_t)CH * K2;
  float* hf = (float*)regB;
  unsigned short* W2th = (unsigned short*)alloc((size_t)HID * K2 * 2);
  unsigned short* W2tl = (unsigned short*)alloc((size_t)HID * K2 * 2);
  float* wa1s = (float*)alloc(NH * IN_F * 4);
  float* wa1d = (float*)alloc(NH * IN_F * 4);
  float* al1s = (float*)alloc((size_t)nN * NH * 4);
  float* al1d = (float*)alloc((size_t)nN * NH * 4);
  float* al2s = (float*)alloc((size_t)nN * 4);
  float* al2d = (float*)alloc((size_t)nN * 4);
  float* alpha1 = (float*)alloc((size_t)Et * NH * 4);
  float* alpha2 = (float*)alloc((size_t)Et * 4);
  int* deg = (int*)alloc((size_t)nN * 4);
  int* off = (int*)alloc((size_t)(nN + 1) * 4);
  int* cursor = (int*)alloc((size_t)nN * 4);
  int* csr = (int*)alloc((size_t)Et * 4);
  (void)n_in; (void)out_size;

  hipMemsetAsync(deg, 0, (size_t)nN * 4, stream);

  // prelims
  k_wa1<<<(NH * IN_F * 64 + 255) / 256, 256, 0, stream>>>(W1, a1s, a1d, wa1s, wa1d);
  k_al1<<<(nN * NH + 255) / 256, 256, 0, stream>>>(x, wa1s, wa1d, al1s, al1d, nN);
  k_cvtW2<<<((K2 / 8) * HID + 255) / 256, 256, 0, stream>>>(W2, W2th, W2tl, HID, K2);

  // CSR by dst
  k_hist<<<(Et + 255) / 256, 256, 0, stream>>>(ei, deg, E, Et);
  k_scan<<<1, 1024, 0, stream>>>(deg, off, cursor, nN);
  k_scatter<<<(Et + 255) / 256, 256, 0, stream>>>(ei, cursor, csr, E, Et);

  // layer-1 softmax
  k_att1<<<(nN * NH + 255) / 256, 256, 0, stream>>>(ei, off, csr, al1s, al1d, alpha1, E, nN);

  // chunked: aggx -> GEMM1 (bias+elu, split-bf16 out) -> GEMM2 (MFMA)
  for (int c0 = 0; c0 < nN; c0 += CH) {
    int rows = (nN - c0 < CH) ? (nN - c0) : CH;
    k_aggx<<<(rows + 3) / 4, 256, 0, stream>>>(x, ei, off, csr, alpha1, xa, E, nN,
                                               c0, c0 + rows);
    {  // h2{h,l}[r, h*512+c] = split_bf16( elu( xa[r,h,:] @ W1[:, h*512+c] + b1 ) )
      dim3 g(rows / 128, HID / 64, NH);
      k_sgemm<3><<<g, 256, 0, stream>>>(xa, W1, b1, nullptr, rows, HID, IN_F,
                                        NH * IN_F, NH * HID, NH * HID,
                                        IN_F, HID, HID, HID, h2h, h2l);
    }
    {  // g2 rows = (h2h+h2l) @ (W2h+W2l), MFMA split-bf16
      dim3 g(rows / 128, HID / 64);
      k_gemm2_mfma<<<g, 256, 0, stream>>>(h2h, h2l, W2th, W2tl,
                                          g2 + (size_t)c0 * HID, rows, HID, K2);
    }
  }

  // layer 2 attention + aggregation
  k_al2<<<(nN * 64 + 255) / 256, 256, 0, stream>>>(g2, a2s, a2d, al2s, al2d, nN);
  k_att2<<<(nN + 255) / 256, 256, 0, stream>>>(ei, off, csr, al2s, al2d, alpha2, E, nN);
  k_agg2<<<(nN + 1) / 2, 256, 0, stream>>>(g2, ei, off, csr, alpha2, b2, h3, E, nN);

  // lin1 + relu
  {
    dim3 g(nN / 128, HID / 64, 1);
    k_sgemm<2><<<g, 256, 0, stream>>>(h3, l1W, l1b, hf, nN, HID, HID,
                                      HID, HID, HID, 0, 0, 0, 0, nullptr, nullptr);
  }

  // pair scoring
  k_pairs<<<(TEn * 64 + 255) / 256, 256, 0, stream>>>(hf, te, f2W, f2b, out, TEn);
}